// Round 1
// baseline (108.149 us; speedup 1.0000x reference)
//
#include <hip/hip_runtime.h>
#include <hip/hip_bf16.h>

#define NFFT    512
#define HOPSZ   128
#define FBINS   257
#define TFR     2048
#define NBC     32            // B*C
#define KPAD    544           // 17 * 32 (K=514 zero-padded)
#define KSTEPS  17
#define OUTLEN  262016        // (T-1)*HOP
#define SPAD    256           // n_fft/2 (center trim)

typedef __bf16 bf16x8 __attribute__((ext_vector_type(8)));
typedef float  f32x4  __attribute__((ext_vector_type(4)));

struct U2x2 { uint2 lo, hi; };   // 16B container for a bf16x8 fragment

static __device__ __forceinline__ float bf2f(unsigned short u) {
    union { unsigned int i; float f; } x; x.i = (unsigned int)u << 16; return x.f;
}

// ---------------------------------------------------------------------------
// Kernel 1: W'[n][k] = window[n] * inverse-rDFT coefficient, bf16 [512][KPAD].
//   k = 2f   -> (c_f/512) * cos(2*pi*f*n/512)
//   k = 2f+1 -> -(c_f/512) * sin(2*pi*f*n/512), zero for f in {0,256}
//   c_f = 1 for f in {0,256}, else 2.  k >= 514 -> 0 (pad).
// ---------------------------------------------------------------------------
__global__ void k_wgen(const float* __restrict__ wnd, __hip_bfloat16* __restrict__ Wp) {
    const int n = blockIdx.x;               // 0..511
    const float wn = wnd[n] * (1.0f / 512.0f);
    for (int k = threadIdx.x; k < KPAD; k += blockDim.x) {
        float val = 0.0f;
        if (k < 2 * FBINS) {
            const int f = k >> 1;
            const bool edge = (f == 0) || (f == 256);
            const float cf = edge ? 1.0f : 2.0f;
            const int m = (f * n) & (NFFT - 1);              // exact arg reduction
            const float ang = (float)m * 0.01227184630308513f; // 2*pi/512
            float s, c;
            __sincosf(ang, &s, &c);
            val = (k & 1) ? (edge ? 0.0f : -cf * wn * s) : (cf * wn * c);
        }
        Wp[n * KPAD + k] = __float2bfloat16(val);
    }
}

// ---------------------------------------------------------------------------
// Kernel 2: frames = W' @ Xb   (M=512, K=544, N=64 per block)
//   grid 1024 blocks, 512 threads (8 waves). BM=512 -> X read from HBM once.
//   Wave w: rows [128*(w>>1), +128), cols [32*(w&1), +32): acc 8x2 of 16x16.
//   Output: windowed frames, bf16, layout [bc*2048 + t][512].
// ---------------------------------------------------------------------------
__global__ __launch_bounds__(512) void k_gemm(
    const float* __restrict__ X,
    const __hip_bfloat16* __restrict__ Wp,
    __hip_bfloat16* __restrict__ frames)
{
    __shared__ __hip_bfloat16 As[512][36];   // 36.9 KB, +4 pad (72B rows)
    __shared__ __hip_bfloat16 Bs[64][36];    //  4.6 KB, t-major [t][k]

    const int tid  = threadIdx.x;
    const int lane = tid & 63;
    const int wv   = tid >> 6;        // 0..7
    const int wr   = wv >> 1;         // row block (128 rows each)
    const int wc   = wv & 1;          // col block (32 cols each)

    const int nflat0 = blockIdx.x * 64;
    const int bc = nflat0 >> 11;          // 64 | 2048, tiles never cross bc
    const int t0 = nflat0 & (TFR - 1);
    const float* Xbc = X + (size_t)bc * FBINS * TFR * 2;

    f32x4 acc[8][2] = {};

    const int a_chunk = tid & 3;          // 4 x 16B per 64B row
    const int a_rbase = tid >> 2;         // 0..127
    const int b_f     = tid >> 5;         // 0..15 (f within step)
    const int b_t     = (tid & 31) * 2;   // 0..62 even

    const int kg  = (lane >> 4) * 4;      // split-K fragment: k = kg+(j&3)+16*(j>>2)
    const int rlo = lane & 15;

    for (int ks = 0; ks < KSTEPS; ++ks) {
        const int k0 = ks * 32;
        __syncthreads();
        // ---- stage A: W'[0..511][k0..k0+32) -> As
        #pragma unroll
        for (int it = 0; it < 4; ++it) {
            const int row = it * 128 + a_rbase;
            uint4 v = *(const uint4*)(Wp + (size_t)row * KPAD + k0 + a_chunk * 8);
            uint2* dst = (uint2*)(&As[row][a_chunk * 8]);   // b64 writes (72B rows)
            dst[0] = make_uint2(v.x, v.y);
            dst[1] = make_uint2(v.z, v.w);
        }
        // ---- stage B: X fp32 -> bf16, Bs[t][k]  (k = 2*f_local + reim)
        {
            const int f = ks * 16 + b_f;
            float4 v = make_float4(0.f, 0.f, 0.f, 0.f);
            if (f < FBINS)                 // f>=257: zero-fill (W' also zero there)
                v = *(const float4*)(Xbc + ((size_t)f * TFR + t0 + b_t) * 2);
            union { ushort2 u; __hip_bfloat16 h[2]; } p0, p1;
            p0.h[0] = __float2bfloat16(v.x);   // re(t)
            p0.h[1] = __float2bfloat16(v.y);   // im(t)
            p1.h[0] = __float2bfloat16(v.z);   // re(t+1)
            p1.h[1] = __float2bfloat16(v.w);   // im(t+1)
            *(ushort2*)(&Bs[b_t][2 * b_f])     = p0.u;
            *(ushort2*)(&Bs[b_t + 1][2 * b_f]) = p1.u;
        }
        __syncthreads();
        // ---- MFMA: 16 per wave per step
        U2x2 braw0, braw1;
        {
            const __hip_bfloat16* bp0 = &Bs[wc * 32 + rlo][kg];
            braw0.lo = *(const uint2*)bp0;
            braw0.hi = *(const uint2*)(bp0 + 16);
            const __hip_bfloat16* bp1 = &Bs[wc * 32 + 16 + rlo][kg];
            braw1.lo = *(const uint2*)bp1;
            braw1.hi = *(const uint2*)(bp1 + 16);
        }
        const bf16x8 bfrag0 = __builtin_bit_cast(bf16x8, braw0);
        const bf16x8 bfrag1 = __builtin_bit_cast(bf16x8, braw1);
        #pragma unroll
        for (int mi = 0; mi < 8; ++mi) {
            const __hip_bfloat16* ap = &As[wr * 128 + mi * 16 + rlo][kg];
            U2x2 araw;
            araw.lo = *(const uint2*)ap;
            araw.hi = *(const uint2*)(ap + 16);
            const bf16x8 afrag = __builtin_bit_cast(bf16x8, araw);
            acc[mi][0] = __builtin_amdgcn_mfma_f32_16x16x32_bf16(afrag, bfrag0, acc[mi][0], 0, 0, 0);
            acc[mi][1] = __builtin_amdgcn_mfma_f32_16x16x32_bf16(afrag, bfrag1, acc[mi][1], 0, 0, 0);
        }
    }
    // ---- epilogue: C/D layout row=(l>>4)*4+reg, col=l&15 (m89-verified)
    const int rrow = (lane >> 4) * 4;
    #pragma unroll
    for (int mi = 0; mi < 8; ++mi) {
        const int nbase = wr * 128 + mi * 16 + rrow;
        #pragma unroll
        for (int ni = 0; ni < 2; ++ni) {
            const int t = t0 + wc * 32 + ni * 16 + rlo;
            union { ushort4 u; __hip_bfloat16 h[4]; } pk;
            pk.h[0] = __float2bfloat16(acc[mi][ni][0]);
            pk.h[1] = __float2bfloat16(acc[mi][ni][1]);
            pk.h[2] = __float2bfloat16(acc[mi][ni][2]);
            pk.h[3] = __float2bfloat16(acc[mi][ni][3]);
            *(ushort4*)((unsigned short*)frames + ((size_t)(bc * TFR + t) * NFFT + nbase)) = pk.u;
        }
    }
}

// ---------------------------------------------------------------------------
// Kernel 3: overlap-add + envelope normalize. 4 outputs / thread.
//   out[bc][o] = sum_r frames[t][n] / sum_r w[n]^2,  t = (s>>7)-r, n = (s&127)+128r
// ---------------------------------------------------------------------------
__global__ __launch_bounds__(256) void k_ola(
    const __hip_bfloat16* __restrict__ frames,
    const float* __restrict__ wnd,
    float* __restrict__ out)
{
    const int bc = blockIdx.y;
    const int o  = (blockIdx.x * 256 + threadIdx.x) * 4;
    if (o >= OUTLEN) return;
    const int s  = o + SPAD;
    const int tb = s >> 7;
    const int nb = s & (HOPSZ - 1);
    const unsigned short* fb = (const unsigned short*)frames + (size_t)bc * TFR * NFFT;
    float y0 = 0.f, y1 = 0.f, y2 = 0.f, y3 = 0.f;
    float e0 = 0.f, e1 = 0.f, e2 = 0.f, e3 = 0.f;
    #pragma unroll
    for (int r = 0; r < 4; ++r) {
        const int t = tb - r;
        if ((unsigned)t > (unsigned)(TFR - 1)) continue;   // same mask for y and env
        const int n = nb + (r << 7);
        ushort4 v = *(const ushort4*)(fb + (size_t)t * NFFT + n);
        float4  w = *(const float4*)(wnd + n);
        y0 += bf2f(v.x); e0 += w.x * w.x;
        y1 += bf2f(v.y); e1 += w.y * w.y;
        y2 += bf2f(v.z); e2 += w.z * w.z;
        y3 += bf2f(v.w); e3 += w.w * w.w;
    }
    float4 res = make_float4(y0 / e0, y1 / e1, y2 / e2, y3 / e3);
    *(float4*)(out + (size_t)bc * OUTLEN + o) = res;
}

// ---------------------------------------------------------------------------
extern "C" void kernel_launch(void* const* d_in, const int* in_sizes, int n_in,
                              void* d_out, int out_size, void* d_ws, size_t ws_size,
                              hipStream_t stream) {
    (void)in_sizes; (void)n_in; (void)out_size; (void)ws_size;
    const float* X   = (const float*)d_in[0];
    const float* wnd = (const float*)d_in[1];
    float* out = (float*)d_out;

    __hip_bfloat16* Wp     = (__hip_bfloat16*)d_ws;                      // 557 KB
    __hip_bfloat16* frames = (__hip_bfloat16*)((char*)d_ws + (1 << 20)); // 64 MB

    k_wgen<<<512, 256, 0, stream>>>(wnd, Wp);
    k_gemm<<<1024, 512, 0, stream>>>(X, Wp, frames);
    k_ola<<<dim3((OUTLEN / 4 + 255) / 256, NBC), 256, 0, stream>>>(frames, wnd, out);
}